// Round 6
// baseline (117.207 us; speedup 1.0000x reference)
//
#include <hip/hip_runtime.h>
#include <math.h>

#define NN 768
#define CC 256
#define TI 3     // rows per k_prep block
#define RT 12    // rows per k_attn block
#define JC 192   // j columns per k_attn block (3 waves per row-triple group)
#define NJC 4    // j chunks: 4 * 192 = 768
#define PSTR 16  // pe row stride (12 rows padded to 16 -> b128-aligned quads)

__device__ __forceinline__ float leaky(float x) { return x >= 0.0f ? x : 0.2f * x; }

__device__ __forceinline__ float waveMax(float v) {
    #pragma unroll
    for (int o = 32; o > 0; o >>= 1) v = fmaxf(v, __shfl_xor(v, o, 64));
    return v;
}
__device__ __forceinline__ float waveSum(float v) {
    #pragma unroll
    for (int o = 32; o > 0; o >>= 1) v += __shfl_xor(v, o, 64);
    return v;
}

// Kernel 1 (unchanged, ~2.5 us): f = features @ FC; g[c][j] = w1*f[j][c]+b;
// D0/D1 = per-row linear-term dots; ut4[triple][c] = {w0*f_r0[c], w0*f_r1[c],
// w0*f_r2[c], 0.4*lin_w[c]} — read by k_attn through the scalar pipe.
__global__ __launch_bounds__(768) void k_prep(
    const float* __restrict__ features,
    const float* __restrict__ FC,
    const float* __restrict__ fc_w,
    const float* __restrict__ fc_b,
    const float* __restrict__ lin_w,
    float* __restrict__ f,
    float* __restrict__ g,
    float* __restrict__ D0,
    float* __restrict__ D1,
    float4* __restrict__ ut4)
{
    __shared__ float sA[TI * CC];
    __shared__ float sF[TI * CC];
    __shared__ float sredD[12], sredW[12];

    const int t  = threadIdx.x;
    const int r  = t >> 8;
    const int c  = t & 255;
    const int i0 = blockIdx.x * TI;

    sA[r * CC + c] = features[(i0 + r) * CC + c];
    __syncthreads();

    float a = 0.f;
    const float* fcp = FC + c;
    const float* ap  = sA + r * CC;
    #pragma unroll 8
    for (int k = 0; k < CC; ++k)
        a = fmaf(ap[k], fcp[k * CC], a);

    const float w1 = fc_w[1], b = fc_b[0];
    f[(i0 + r) * CC + c] = a;
    g[c * NN + i0 + r]   = fmaf(w1, a, b);
    sF[r * CC + c] = a;

    const float lw = lin_w[c];
    float dv = waveSum(lw * a);
    float wv = waveSum(lw);
    const int wid = t >> 6;
    if ((t & 63) == 0) { sredD[wid] = dv; sredW[wid] = wv; }
    __syncthreads();
    if (t < TI) {
        float D = sredD[t*4] + sredD[t*4+1] + sredD[t*4+2] + sredD[t*4+3];
        float W = sredW[t*4] + sredW[t*4+1] + sredW[t*4+2] + sredW[t*4+3];
        D0[i0 + t] = fc_w[0] * D;
        D1[i0 + t] = fmaf(w1, D, b * W);
    }
    if (t < CC) {
        const float w0 = fc_w[0];
        ut4[blockIdx.x * CC + t] = make_float4(w0 * sF[t],
                                               w0 * sF[CC + t],
                                               w0 * sF[2*CC + t],
                                               0.4f * lin_w[t]);
    }
}

// Kernel 2: split-j partial attention, DS-light. Block = 12 rows x 192-j
// chunk (256 blocks -> g/f re-read traffic 96 MB, 4x less than full-j).
// Phase 1: thread (q=t/192 -> rows 3q..3q+2, jj=t%192); u via SCALAR loads
// (q made provably wave-uniform with readfirstlane). Phase 3: wave (rg,jw)
// owns 4 rows x 48 j; lane owns 4 channels; pp via one b128 broadcast per j.
__global__ __launch_bounds__(768) void k_attn(
    const float* __restrict__ f,      // [N][C]
    const float* __restrict__ g,      // [C][N]
    const float4* __restrict__ ut4,   // [N/3][C]
    const float* __restrict__ D0,     // [N]
    const float* __restrict__ D1,     // [N]
    const float* __restrict__ coords, // [N][3]
    const float* __restrict__ sc_w,
    const float* __restrict__ sc_b,
    const float* __restrict__ lin_w,  // [C+3]
    const float* __restrict__ lin_b,
    float* __restrict__ hp,           // [NJC][N][C] partial sums
    float* __restrict__ Mp,           // [N][NJC] partial max
    float* __restrict__ Lp)           // [N][NJC] partial expsum
{
    __shared__ float pe[JC * PSTR];     // 12 KB: pe[jj][row 0..11, pad 16]
    __shared__ float hpart[12][4][CC];  // 48 KB: [wave][row-in-quad][channel]
    __shared__ float sredm[12][3];
    __shared__ float sreds[12][3];

    const int t    = threadIdx.x;
    const int it   = blockIdx.x >> 2;
    const int jc   = blockIdx.x & 3;
    const int i0   = it * RT;
    const int jb   = jc * JC;
    const int q    = t / JC;          // 0..3, uniform per wave (192 = 3 waves)
    const int jj   = t - q * JC;      // 0..191
    const int j    = jb + jj;
    const int w    = t >> 6;
    const int lane = t & 63;

    // ---- Phase 1: 0.4*wc*|u_r + g_j| over c, rows 3q..3q+2, own j ----
    float a0 = 0.f, a1 = 0.f, a2 = 0.f;
    const int qu = __builtin_amdgcn_readfirstlane(q);   // force SGPR address
    const float4* up = ut4 + (size_t)(it * 4 + qu) * CC; // -> s_load_dwordx4
    const float*  gp = g + j;
    #pragma unroll 8
    for (int c = 0; c < CC; ++c) {
        float  gj = gp[c * NN];       // coalesced; q-replicas hit L1
        float4 u  = up[c];            // scalar pipe
        a0 = fmaf(u.w, fabsf(u.x + gj), a0);
        a1 = fmaf(u.w, fabsf(u.y + gj), a1);
        a2 = fmaf(u.w, fabsf(u.z + gj), a2);
    }

    // coord part + 0.6-linear part + outer leaky
    const float sw0 = sc_w[0], sw1 = sc_w[1], sb = sc_b[0], lb = lin_b[0];
    const float lw30 = lin_w[CC], lw31 = lin_w[CC+1], lw32 = lin_w[CC+2];
    const float cj0 = fmaf(sw1, coords[j*3+0], sb);
    const float cj1 = fmaf(sw1, coords[j*3+1], sb);
    const float cj2 = fmaf(sw1, coords[j*3+2], sb);
    const float d1  = D1[j];
    float accs[3] = {a0, a1, a2};
    float scv[3];
    #pragma unroll
    for (int rr = 0; rr < 3; ++rr) {
        const int i = i0 + 3*q + rr;
        float sd = lw30 * leaky(fmaf(sw0, coords[i*3+0], cj0))
                 + lw31 * leaky(fmaf(sw0, coords[i*3+1], cj1))
                 + lw32 * leaky(fmaf(sw0, coords[i*3+2], cj2));
        scv[rr] = leaky(accs[rr] + sd + 0.6f * (D0[i] + d1) + lb);
    }

    // ---- Phase 2: per-(row, chunk) partial softmax over 192 j ----
    #pragma unroll
    for (int rr = 0; rr < 3; ++rr) {
        float v = waveMax(scv[rr]);
        if (lane == 0) sredm[w][rr] = v;
    }
    __syncthreads();
    float m[3];
    #pragma unroll
    for (int rr = 0; rr < 3; ++rr)
        m[rr] = fmaxf(fmaxf(sredm[3*q][rr], sredm[3*q+1][rr]), sredm[3*q+2][rr]);

    float e[3];
    #pragma unroll
    for (int rr = 0; rr < 3; ++rr) {
        e[rr] = __expf(scv[rr] - m[rr]);
        pe[jj * PSTR + 3*q + rr] = e[rr];   // lanes stride-16 -> 2-way (free)
        float v = waveSum(e[rr]);
        if (lane == 0) sreds[w][rr] = v;
    }
    __syncthreads();   // publishes pe + sreds
    if (jj == 0) {
        #pragma unroll
        for (int rr = 0; rr < 3; ++rr) {
            float l = sreds[3*q][rr] + sreds[3*q+1][rr] + sreds[3*q+2][rr];
            Mp[(i0 + 3*q + rr) * NJC + jc] = m[rr];
            Lp[(i0 + 3*q + rr) * NJC + jc] = l;
        }
    }

    // ---- Phase 3: wave w=(rg=w>>2, jw=w&3): rows 4rg..4rg+3, j-slice jw ----
    const int rg = w >> 2;
    const int jw = w & 3;
    float4 h0 = make_float4(0.f,0.f,0.f,0.f);
    float4 h1 = h0, h2 = h0, h3 = h0;
    const float4* f4 = (const float4*)f;       // [N][64] float4
    const int jbase = jb + jw * 48;
    const float* peb = pe + 4 * rg;            // 16B-aligned quad of rows
    #pragma unroll 4
    for (int jx = 0; jx < 48; ++jx) {
        const int jl = jw * 48 + jx;           // block-local j
        float4 fv = f4[(size_t)(jbase + jx) * 64 + lane];  // coalesced 1KB/wave
        float4 e4 = *(const float4*)(peb + jl * PSTR);     // b128 broadcast
        h0.x = fmaf(e4.x, fv.x, h0.x); h0.y = fmaf(e4.x, fv.y, h0.y);
        h0.z = fmaf(e4.x, fv.z, h0.z); h0.w = fmaf(e4.x, fv.w, h0.w);
        h1.x = fmaf(e4.y, fv.x, h1.x); h1.y = fmaf(e4.y, fv.y, h1.y);
        h1.z = fmaf(e4.y, fv.z, h1.z); h1.w = fmaf(e4.y, fv.w, h1.w);
        h2.x = fmaf(e4.z, fv.x, h2.x); h2.y = fmaf(e4.z, fv.y, h2.y);
        h2.z = fmaf(e4.z, fv.z, h2.z); h2.w = fmaf(e4.z, fv.w, h2.w);
        h3.x = fmaf(e4.w, fv.x, h3.x); h3.y = fmaf(e4.w, fv.y, h3.y);
        h3.z = fmaf(e4.w, fv.z, h3.z); h3.w = fmaf(e4.w, fv.w, h3.w);
    }
    *(float4*)&hpart[w][0][4*lane] = h0;
    *(float4*)&hpart[w][1][4*lane] = h1;
    *(float4*)&hpart[w][2][4*lane] = h2;
    *(float4*)&hpart[w][3][4*lane] = h3;
    __syncthreads();

    // ---- Reduce over the 4 jw partials per row-quad; store hp ----
    {
        const int rgrp = t >> 8;     // 0..2 (row-quad group)
        const int c    = t & 255;
        #pragma unroll
        for (int k = 0; k < 4; ++k) {
            float h = hpart[rgrp*4 + 0][k][c] + hpart[rgrp*4 + 1][k][c]
                    + hpart[rgrp*4 + 2][k][c] + hpart[rgrp*4 + 3][k][c];
            const int row = i0 + rgrp*4 + k;
            hp[((size_t)jc * NN + row) * CC + c] = h;
        }
    }
}

// Kernel 3: combine the 4 j-chunk partials per row, normalize, elu.
__global__ __launch_bounds__(256) void k_comb(
    const float* __restrict__ hp,
    const float* __restrict__ Mp,
    const float* __restrict__ Lp,
    float* __restrict__ out)
{
    const int t = threadIdx.x;
    const int i = blockIdx.x;

    float m0 = Mp[i*NJC+0], m1 = Mp[i*NJC+1], m2 = Mp[i*NJC+2], m3 = Mp[i*NJC+3];
    float M  = fmaxf(fmaxf(m0, m1), fmaxf(m2, m3));
    float w0 = __expf(m0 - M), w1 = __expf(m1 - M);
    float w2 = __expf(m2 - M), w3 = __expf(m3 - M);
    float den = w0*Lp[i*NJC+0] + w1*Lp[i*NJC+1] + w2*Lp[i*NJC+2] + w3*Lp[i*NJC+3];
    float inv = 1.0f / den;

    float num = w0 * hp[((size_t)0*NN + i)*CC + t]
              + w1 * hp[((size_t)1*NN + i)*CC + t]
              + w2 * hp[((size_t)2*NN + i)*CC + t]
              + w3 * hp[((size_t)3*NN + i)*CC + t];
    float v = num * inv;
    out[i*CC + t] = (v > 0.f) ? v : (__expf(v) - 1.0f);
}

extern "C" void kernel_launch(void* const* d_in, const int* in_sizes, int n_in,
                              void* d_out, int out_size, void* d_ws, size_t ws_size,
                              hipStream_t stream) {
    const float* features = (const float*)d_in[0];
    const float* coords   = (const float*)d_in[1];
    // d_in[2] = adj, unused by forward
    const float* FC       = (const float*)d_in[3];
    const float* fc_w     = (const float*)d_in[4];
    const float* fc_b     = (const float*)d_in[5];
    const float* sc_w     = (const float*)d_in[6];
    const float* sc_b     = (const float*)d_in[7];
    const float* lin_w    = (const float*)d_in[8];
    const float* lin_b    = (const float*)d_in[9];
    float* out = (float*)d_out;

    float* f  = (float*)d_ws;              // N*C
    float* g  = f  + NN*CC;                // C*N
    float* D0 = g  + CC*NN;                // N
    float* D1 = D0 + NN;                   // N
    float* Mp = D1 + NN;                   // N*NJC
    float* Lp = Mp + NN*NJC;               // N*NJC
    float* hp = Lp + NN*NJC;               // NJC*N*C
    float4* ut4;
    {
        size_t off = (size_t)((char*)(hp + (size_t)NJC*NN*CC) - (char*)d_ws);
        off = (off + 15) & ~(size_t)15;
        ut4 = (float4*)((char*)d_ws + off); // (N/3)*C float4, 16B-aligned
    }

    k_prep<<<NN/TI, 768, 0, stream>>>(features, FC, fc_w, fc_b, lin_w, f, g, D0, D1, ut4);
    k_attn<<<(NN/RT)*NJC, 768, 0, stream>>>(f, g, ut4, D0, D1, coords, sc_w, sc_b,
                                            lin_w, lin_b, hp, Mp, Lp);
    k_comb<<<NN, 256, 0, stream>>>(hp, Mp, Lp, out);
}

// Round 7
// 116.885 us; speedup vs baseline: 1.0028x; 1.0028x over previous
//
#include <hip/hip_runtime.h>
#include <math.h>

#define NN 768
#define CC 256
#define TI 3     // rows per block (both kernels)
#define JC 256   // j columns per k_attn block
#define NJC 3    // j chunks: 3 * 256 = 768

__device__ __forceinline__ float leaky(float x) { return x >= 0.0f ? x : 0.2f * x; }

__device__ __forceinline__ float waveMax(float v) {
    #pragma unroll
    for (int o = 32; o > 0; o >>= 1) v = fmaxf(v, __shfl_xor(v, o, 64));
    return v;
}
__device__ __forceinline__ float waveSum(float v) {
    #pragma unroll
    for (int o = 32; o > 0; o >>= 1) v += __shfl_xor(v, o, 64);
    return v;
}

// Kernel 1 (unchanged, ~2.5 us): f = features @ FC; g[c][j] = w1*f[j][c]+b;
// D0/D1 = per-row linear-term dots; ut4[triple][c] = {w0*f_r0[c], w0*f_r1[c],
// w0*f_r2[c], 0.4*lin_w[c]} — read by k_attn through the scalar pipe.
__global__ __launch_bounds__(768) void k_prep(
    const float* __restrict__ features,
    const float* __restrict__ FC,
    const float* __restrict__ fc_w,
    const float* __restrict__ fc_b,
    const float* __restrict__ lin_w,
    float* __restrict__ f,
    float* __restrict__ g,
    float* __restrict__ D0,
    float* __restrict__ D1,
    float4* __restrict__ ut4)
{
    __shared__ float sA[TI * CC];
    __shared__ float sF[TI * CC];
    __shared__ float sredD[12], sredW[12];

    const int t  = threadIdx.x;
    const int r  = t >> 8;
    const int c  = t & 255;
    const int i0 = blockIdx.x * TI;

    sA[r * CC + c] = features[(i0 + r) * CC + c];
    __syncthreads();

    float a = 0.f;
    const float* fcp = FC + c;
    const float* ap  = sA + r * CC;
    #pragma unroll 8
    for (int k = 0; k < CC; ++k)
        a = fmaf(ap[k], fcp[k * CC], a);

    const float w1 = fc_w[1], b = fc_b[0];
    f[(i0 + r) * CC + c] = a;
    g[c * NN + i0 + r]   = fmaf(w1, a, b);
    sF[r * CC + c] = a;

    const float lw = lin_w[c];
    float dv = waveSum(lw * a);
    float wv = waveSum(lw);
    const int wid = t >> 6;
    if ((t & 63) == 0) { sredD[wid] = dv; sredW[wid] = wv; }
    __syncthreads();
    if (t < TI) {
        float D = sredD[t*4] + sredD[t*4+1] + sredD[t*4+2] + sredD[t*4+3];
        float W = sredW[t*4] + sredW[t*4+1] + sredW[t*4+2] + sredW[t*4+3];
        D0[i0 + t] = fc_w[0] * D;
        D1[i0 + t] = fmaf(w1, D, b * W);
    }
    if (t < CC) {
        const float w0 = fc_w[0];
        ut4[blockIdx.x * CC + t] = make_float4(w0 * sF[t],
                                               w0 * sF[CC + t],
                                               w0 * sF[2*CC + t],
                                               0.4f * lin_w[t]);
    }
}

// Kernel 2: 768 blocks x 256 threads (4 waves) -> 3 blocks/CU. Block =
// (row-triple it, j-chunk jc of 256). Same instruction counts as round 5/6;
// the change is occupancy: independent blocks overlap each other's latency
// stalls and barriers (1-block/CU was the round-5/6 limiter).
__global__ __launch_bounds__(256) void k_attn(
    const float* __restrict__ f,      // [N][C]
    const float* __restrict__ g,      // [C][N]
    const float4* __restrict__ ut4,   // [N/3][C]
    const float* __restrict__ D0,     // [N]
    const float* __restrict__ D1,     // [N]
    const float* __restrict__ coords, // [N][3]
    const float* __restrict__ sc_w,
    const float* __restrict__ sc_b,
    const float* __restrict__ lin_w,  // [C+3]
    const float* __restrict__ lin_b,
    float* __restrict__ hp,           // [NJC][N][C] partial sums
    float* __restrict__ Mp,           // [N][NJC] partial max
    float* __restrict__ Lp)           // [N][NJC] partial expsum
{
    __shared__ float4 pp[JC];           // 4 KB: {e0,e1,e2,-} per block-local j
    __shared__ float  hpart[4][TI][CC]; // 12 KB: per-wave h partials
    __shared__ float4 sredm4[4];
    __shared__ float4 sreds4[4];

    const int t    = threadIdx.x;
    const int it   = blockIdx.x & 255;  // row-triple
    const int jc   = blockIdx.x >> 8;   // j-chunk 0..2
    const int i0   = it * TI;
    const int jb   = jc * JC;
    const int j    = jb + t;
    const int w    = t >> 6;
    const int lane = t & 63;

    // ---- Phase 1: 0.4*wc*|u_r + g_j| over c; thread owns one j, 3 rows ----
    float a0 = 0.f, a1 = 0.f, a2 = 0.f;
    const float4* up = ut4 + (size_t)it * CC;   // block-uniform -> s_load_dwordx4
    const float*  gp = g + j;
    #pragma unroll 8
    for (int c = 0; c < CC; ++c) {
        float  gj = gp[c * NN];       // coalesced 256B/wave, L2
        float4 u  = up[c];            // scalar pipe (SGPRs)
        a0 = fmaf(u.w, fabsf(u.x + gj), a0);
        a1 = fmaf(u.w, fabsf(u.y + gj), a1);
        a2 = fmaf(u.w, fabsf(u.z + gj), a2);
    }

    // coord part + 0.6-linear part + outer leaky
    const float sw0 = sc_w[0], sw1 = sc_w[1], sb = sc_b[0], lb = lin_b[0];
    const float lw30 = lin_w[CC], lw31 = lin_w[CC+1], lw32 = lin_w[CC+2];
    const float cj0 = fmaf(sw1, coords[j*3+0], sb);
    const float cj1 = fmaf(sw1, coords[j*3+1], sb);
    const float cj2 = fmaf(sw1, coords[j*3+2], sb);
    const float d1  = D1[j];
    float accs[3] = {a0, a1, a2};
    float scv[3];
    #pragma unroll
    for (int rr = 0; rr < TI; ++rr) {
        const int i = i0 + rr;
        float sd = lw30 * leaky(fmaf(sw0, coords[i*3+0], cj0))
                 + lw31 * leaky(fmaf(sw0, coords[i*3+1], cj1))
                 + lw32 * leaky(fmaf(sw0, coords[i*3+2], cj2));
        scv[rr] = leaky(accs[rr] + sd + 0.6f * (D0[i] + d1) + lb);
    }

    // ---- Phase 2: partial softmax over this block's 256 j ----
    {
        float v0 = waveMax(scv[0]);
        float v1 = waveMax(scv[1]);
        float v2 = waveMax(scv[2]);
        if (lane == 0) sredm4[w] = make_float4(v0, v1, v2, 0.f);
    }
    __syncthreads();
    float m[TI];
    {
        float4 x0 = sredm4[0], x1 = sredm4[1], x2 = sredm4[2], x3 = sredm4[3];
        m[0] = fmaxf(fmaxf(x0.x, x1.x), fmaxf(x2.x, x3.x));
        m[1] = fmaxf(fmaxf(x0.y, x1.y), fmaxf(x2.y, x3.y));
        m[2] = fmaxf(fmaxf(x0.z, x1.z), fmaxf(x2.z, x3.z));
    }
    float e0 = __expf(scv[0] - m[0]);
    float e1 = __expf(scv[1] - m[1]);
    float e2 = __expf(scv[2] - m[2]);
    pp[t] = make_float4(e0, e1, e2, 0.f);
    {
        float v0 = waveSum(e0);
        float v1 = waveSum(e1);
        float v2 = waveSum(e2);
        if (lane == 0) sreds4[w] = make_float4(v0, v1, v2, 0.f);
    }
    __syncthreads();   // publishes pp + sreds4
    if (t < TI) {
        float4 s0 = sreds4[0], s1 = sreds4[1], s2 = sreds4[2], s3 = sreds4[3];
        float l = (t == 0) ? (s0.x + s1.x + s2.x + s3.x)
                : (t == 1) ? (s0.y + s1.y + s2.y + s3.y)
                           : (s0.z + s1.z + s2.z + s3.z);
        float mm = (t == 0) ? m[0] : (t == 1) ? m[1] : m[2];
        Mp[(i0 + t) * NJC + jc] = mm;
        Lp[(i0 + t) * NJC + jc] = l;
    }

    // ---- Phase 3: wave w owns j-slice [64w,64w+64); lane owns 4 channels ----
    float4 h0 = make_float4(0.f,0.f,0.f,0.f);
    float4 h1 = h0, h2 = h0;
    const float4* f4 = (const float4*)f;   // [N][64] float4
    const int jsl = w * 64;
    #pragma unroll 4
    for (int jx = 0; jx < 64; ++jx) {
        const int jl = jsl + jx;
        float4 fv = f4[(size_t)(jb + jl) * 64 + lane];  // coalesced 1KB/wave
        float4 e  = pp[jl];                              // b128 broadcast
        h0.x = fmaf(e.x, fv.x, h0.x); h0.y = fmaf(e.x, fv.y, h0.y);
        h0.z = fmaf(e.x, fv.z, h0.z); h0.w = fmaf(e.x, fv.w, h0.w);
        h1.x = fmaf(e.y, fv.x, h1.x); h1.y = fmaf(e.y, fv.y, h1.y);
        h1.z = fmaf(e.y, fv.z, h1.z); h1.w = fmaf(e.y, fv.w, h1.w);
        h2.x = fmaf(e.z, fv.x, h2.x); h2.y = fmaf(e.z, fv.y, h2.y);
        h2.z = fmaf(e.z, fv.z, h2.z); h2.w = fmaf(e.z, fv.w, h2.w);
    }
    *(float4*)&hpart[w][0][4*lane] = h0;
    *(float4*)&hpart[w][1][4*lane] = h1;
    *(float4*)&hpart[w][2][4*lane] = h2;
    __syncthreads();

    // ---- Reduce the 4 wave-partials per row; store hp ----
    #pragma unroll
    for (int r = 0; r < TI; ++r) {
        float h = hpart[0][r][t] + hpart[1][r][t] + hpart[2][r][t] + hpart[3][r][t];
        hp[((size_t)jc * NN + i0 + r) * CC + t] = h;
    }
}

// Kernel 3: combine the 3 j-chunk partials per row, normalize, elu.
__global__ __launch_bounds__(256) void k_comb(
    const float* __restrict__ hp,
    const float* __restrict__ Mp,
    const float* __restrict__ Lp,
    float* __restrict__ out)
{
    const int t = threadIdx.x;
    const int i = blockIdx.x;

    float m0 = Mp[i*NJC+0], m1 = Mp[i*NJC+1], m2 = Mp[i*NJC+2];
    float M  = fmaxf(fmaxf(m0, m1), m2);
    float w0 = __expf(m0 - M), w1 = __expf(m1 - M), w2 = __expf(m2 - M);
    float den = w0*Lp[i*NJC+0] + w1*Lp[i*NJC+1] + w2*Lp[i*NJC+2];
    float inv = 1.0f / den;

    float num = w0 * hp[((size_t)0*NN + i)*CC + t]
              + w1 * hp[((size_t)1*NN + i)*CC + t]
              + w2 * hp[((size_t)2*NN + i)*CC + t];
    float v = num * inv;
    out[i*CC + t] = (v > 0.f) ? v : (__expf(v) - 1.0f);
}

extern "C" void kernel_launch(void* const* d_in, const int* in_sizes, int n_in,
                              void* d_out, int out_size, void* d_ws, size_t ws_size,
                              hipStream_t stream) {
    const float* features = (const float*)d_in[0];
    const float* coords   = (const float*)d_in[1];
    // d_in[2] = adj, unused by forward
    const float* FC       = (const float*)d_in[3];
    const float* fc_w     = (const float*)d_in[4];
    const float* fc_b     = (const float*)d_in[5];
    const float* sc_w     = (const float*)d_in[6];
    const float* sc_b     = (const float*)d_in[7];
    const float* lin_w    = (const float*)d_in[8];
    const float* lin_b    = (const float*)d_in[9];
    float* out = (float*)d_out;

    float* f  = (float*)d_ws;              // N*C
    float* g  = f  + NN*CC;                // C*N
    float* D0 = g  + CC*NN;                // N
    float* D1 = D0 + NN;                   // N
    float* Mp = D1 + NN;                   // N*NJC
    float* Lp = Mp + NN*NJC;               // N*NJC
    float* hp = Lp + NN*NJC;               // NJC*N*C
    float4* ut4;
    {
        size_t off = (size_t)((char*)(hp + (size_t)NJC*NN*CC) - (char*)d_ws);
        off = (off + 15) & ~(size_t)15;
        ut4 = (float4*)((char*)d_ws + off); // (N/3)*C float4, 16B-aligned
    }

    k_prep<<<NN/TI, 768, 0, stream>>>(features, FC, fc_w, fc_b, lin_w, f, g, D0, D1, ut4);
    k_attn<<<(NN/TI)*NJC, 256, 0, stream>>>(f, g, ut4, D0, D1, coords, sc_w, sc_b,
                                            lin_w, lin_b, hp, Mp, Lp);
    k_comb<<<NN, 256, 0, stream>>>(hp, Mp, Lp, out);
}